// Round 1
// baseline (1000.880 us; speedup 1.0000x reference)
//
#include <hip/hip_runtime.h>
#include <math.h>

#define W 512
#define H 512
#define S (W * H)      // 262144 pixels per image
#define B 8            // batch
#define NIMG 16        // 8 pred + 8 true
#define TS 64          // core tile
#define HALO 2
#define LD (TS + 2 * HALO)  // 68

#define FINF __builtin_huge_valf()

// ---------------------------------------------------------------- reductions
__device__ inline float blockReduceSum(float v) {
    __shared__ float sw[4];
    for (int o = 32; o; o >>= 1) v += __shfl_down(v, o);
    int lane = threadIdx.x & 63, wid = threadIdx.x >> 6;
    if (lane == 0) sw[wid] = v;
    __syncthreads();
    float r = 0.f;
    if (threadIdx.x < 4) r = sw[threadIdx.x];
    if (wid == 0) {
        r += __shfl_down(r, 2);
        r += __shfl_down(r, 1);
    }
    __syncthreads();   // make sw reusable by a subsequent call
    return r;          // valid in thread 0
}

// ---------------------------------------------------------------- init
// acc layout (doubles): [0]=inter [1]=sum_p [2]=sum_y ; [3 + img*3 + {0,1,2}] =
// per-image {sum_ep, sum_ep*y, sum_ep*x} for img 0..15.
__global__ void init_acc_kernel(double* acc) {
    int i = threadIdx.x;
    if (i < 51) acc[i] = 0.0;
}

// ---------------------------------------------------------------- phase 1
// softmax fg prob, y cast, skel zero-init, dice partial sums.
__global__ __launch_bounds__(256) void phase1_kernel(
        const float* __restrict__ net, const int* __restrict__ yt,
        float* __restrict__ J0, float* __restrict__ skel,
        double* __restrict__ acc) {
    float inter = 0.f, sp = 0.f, sy = 0.f;
    const int total = B * S;
    for (int i = blockIdx.x * blockDim.x + threadIdx.x; i < total;
         i += gridDim.x * blockDim.x) {
        int b = i / S, s = i - b * S;
        float x0v = net[(size_t)b * 2 * S + s];
        float x1v = net[(size_t)b * 2 * S + S + s];
        float p = 1.f / (1.f + expf(x0v - x1v));   // softmax[:,1]
        float yv = (float)yt[i];
        J0[i] = p;                                  // pred image b
        J0[(size_t)(B + b) * S + s] = yv;           // true image b
        skel[i] = 0.f;
        skel[(size_t)(B + b) * S + s] = 0.f;
        inter += yv * p; sp += p; sy += yv;
    }
    float r;
    r = blockReduceSum(inter); if (threadIdx.x == 0) atomicAdd(&acc[0], (double)r);
    r = blockReduceSum(sp);    if (threadIdx.x == 0) atomicAdd(&acc[1], (double)r);
    r = blockReduceSum(sy);    if (threadIdx.x == 0) atomicAdd(&acc[2], (double)r);
}

// ---------------------------------------------------------------- skeleton round
// One round: E = erode(Jin) [cross-min, +inf OOB]; D = dilate(E) [3x3 max,
// -inf OOB]; delta = relu(Jin - D); skel += relu(delta - skel*delta);
// Jout = E.  Jin/Jout double-buffered (halo race), skel in place (pointwise).
__global__ __launch_bounds__(256) void skel_iter_kernel(
        const float* __restrict__ Jin, float* __restrict__ Jout,
        float* __restrict__ skel) {
    __shared__ float sJ[LD][LD];
    __shared__ float sE[LD][LD];   // valid rows/cols 1..66

    int img = blockIdx.x >> 6;
    int t64 = blockIdx.x & 63;
    int ty = t64 >> 3, tx = t64 & 7;
    int y0 = ty * TS - HALO, x0 = tx * TS - HALO;
    const float* Ji = Jin + (size_t)img * S;
    float* Jo = Jout + (size_t)img * S;
    float* Sk = skel + (size_t)img * S;
    int tid = threadIdx.x;

    // load 68x68 tile (+inf outside image)
    for (int idx = tid; idx < LD * LD; idx += 256) {
        int r = idx / LD, c = idx - r * LD;
        int y = y0 + r, x = x0 + c;
        float v = FINF;
        if (y >= 0 && y < H && x >= 0 && x < W) v = Ji[y * W + x];
        sJ[r][c] = v;
    }
    __syncthreads();

    // erode on 66x66 (positions outside image -> -inf so dilate ignores them)
    for (int idx = tid; idx < 66 * 66; idx += 256) {
        int r = idx / 66 + 1, c = idx % 66 + 1;
        int y = y0 + r, x = x0 + c;
        float v;
        if (y >= 0 && y < H && x >= 0 && x < W) {
            v = sJ[r][c];
            v = fminf(v, sJ[r - 1][c]);
            v = fminf(v, sJ[r + 1][c]);
            v = fminf(v, sJ[r][c - 1]);
            v = fminf(v, sJ[r][c + 1]);
        } else {
            v = -FINF;
        }
        sE[r][c] = v;
    }
    __syncthreads();

    // core 64x64: dilate + delta + skel update + write new img
    for (int idx = tid; idx < TS * TS; idx += 256) {
        int r = (idx >> 6) + HALO, c = (idx & 63) + HALO;
        int y = y0 + r, x = x0 + c;          // always in-image (512 % 64 == 0)
        float d = sE[r - 1][c - 1];
        d = fmaxf(d, sE[r - 1][c]); d = fmaxf(d, sE[r - 1][c + 1]);
        d = fmaxf(d, sE[r][c - 1]); d = fmaxf(d, sE[r][c]); d = fmaxf(d, sE[r][c + 1]);
        d = fmaxf(d, sE[r + 1][c - 1]); d = fmaxf(d, sE[r + 1][c]); d = fmaxf(d, sE[r + 1][c + 1]);
        float delta = fmaxf(sJ[r][c] - d, 0.f);
        size_t gi = (size_t)y * W + x;
        float s = Sk[gi];
        s += fmaxf(delta - s * delta, 0.f);
        Sk[gi] = s;
        Jo[gi] = sE[r][c];
    }
}

// ---------------------------------------------------------------- endpoints
// ns = 3x3 sum (zero pad) + 9*center ; ep = exp(-(ns-11)^2)*skel ;
// per-image sums {ep, ep*y, ep*x}.
__global__ __launch_bounds__(256) void endpoint_kernel(
        const float* __restrict__ skel, double* __restrict__ acc) {
    int img = blockIdx.x >> 8;     // 256 blocks/image, 2 rows each
    int rb = blockIdx.x & 255;
    const float* Sk = skel + (size_t)img * S;
    int tid = threadIdx.x;
    float t = 0.f, syA = 0.f, sxA = 0.f;
    for (int k = 0; k < 4; ++k) {
        int idx = tid + k * 256;          // 0..1023 over a 2x512 strip
        int y = rb * 2 + (idx >> 9);
        int x = idx & 511;
        float sc = Sk[y * W + x];
        float ns = 9.f * sc;              // center weight 10 = 1 + 9
        for (int dy = -1; dy <= 1; ++dy) {
            int yy = y + dy; if (yy < 0 || yy >= H) continue;
            for (int dx = -1; dx <= 1; ++dx) {
                int xx = x + dx; if (xx < 0 || xx >= W) continue;
                ns += Sk[yy * W + xx];
            }
        }
        float e = ns - 11.f;
        float ep = expf(-e * e) * sc;     // GAMMA = 1
        t += ep; syA += ep * (float)y; sxA += ep * (float)x;
    }
    float r;
    r = blockReduceSum(t);   if (threadIdx.x == 0) atomicAdd(&acc[3 + img * 3 + 0], (double)r);
    r = blockReduceSum(syA); if (threadIdx.x == 0) atomicAdd(&acc[3 + img * 3 + 1], (double)r);
    r = blockReduceSum(sxA); if (threadIdx.x == 0) atomicAdd(&acc[3 + img * 3 + 2], (double)r);
}

// ---------------------------------------------------------------- final scalar
__global__ void final_kernel(const double* __restrict__ acc, float* __restrict__ out) {
    if (threadIdx.x == 0) {
        double inter = acc[0], sp = acc[1], sy = acc[2];
        double dsum = 0.0, csum = 0.0;
        for (int b = 0; b < B; ++b) {
            double tp  = acc[3 + b * 3 + 0];
            double typ = acc[3 + b * 3 + 1];
            double txp = acc[3 + b * 3 + 2];
            double tt  = acc[3 + (B + b) * 3 + 0];
            double tyt = acc[3 + (B + b) * 3 + 1];
            double txt = acc[3 + (B + b) * 3 + 2];
            double ycp = typ / (tp + 1e-8), xcp = txp / (tp + 1e-8);
            double yct = tyt / (tt + 1e-8), xct = txt / (tt + 1e-8);
            double dy = ycp - yct, dx = xcp - xct;
            dsum += sqrt(dy * dy + dx * dx);
            csum += fabs(tp - tt) / (tp + tt + 1e-8);
        }
        double diag = sqrt((double)(H * H + W * W));
        double distance_loss = (dsum / B) / (diag * 1.0 /*TAU*/ + 1e-8);
        double count_penalty = csum / B;
        double dice = 1.0 - (2.0 * inter + 1.0) / (sy + sp + 1.0);
        out[0] = (float)(0.85 * dice + 0.15 * (distance_loss + count_penalty));
    }
}

// ---------------------------------------------------------------- launch
extern "C" void kernel_launch(void* const* d_in, const int* in_sizes, int n_in,
                              void* d_out, int out_size, void* d_ws, size_t ws_size,
                              hipStream_t stream) {
    const float* net = (const float*)d_in[0];   // [8,2,512,512] f32
    const int*   yt  = (const int*)d_in[1];     // [8,1,512,512] i32
    float* out = (float*)d_out;

    float* J0   = (float*)d_ws;                      // 16 MB
    float* J1   = J0 + (size_t)NIMG * S;             // 16 MB
    float* skel = J1 + (size_t)NIMG * S;             // 16 MB
    double* acc = (double*)(skel + (size_t)NIMG * S);

    hipLaunchKernelGGL(init_acc_kernel, dim3(1), dim3(64), 0, stream, acc);
    hipLaunchKernelGGL(phase1_kernel, dim3(2048), dim3(256), 0, stream,
                       net, yt, J0, skel, acc);

    float* a = J0; float* b = J1;
    for (int k = 0; k <= 40; ++k) {   // 41 rounds = init + 40 scan steps
        hipLaunchKernelGGL(skel_iter_kernel, dim3(NIMG * 64), dim3(256), 0, stream,
                           a, b, skel);
        float* tmp = a; a = b; b = tmp;
    }

    hipLaunchKernelGGL(endpoint_kernel, dim3(NIMG * 256), dim3(256), 0, stream,
                       skel, acc);
    hipLaunchKernelGGL(final_kernel, dim3(1), dim3(64), 0, stream, acc, out);
}

// Round 2
// 476.790 us; speedup vs baseline: 2.0992x; 2.0992x over previous
//
#include <hip/hip_runtime.h>
#include <math.h>

#define W 512
#define H 512
#define S (W * H)        // 262144
#define B 8
#define NIMG 16
#define CORE 64
#define HALO 12
#define LDT 88           // CORE + 2*HALO
#define NQ (LDT / 4)     // 22 quads per tile row
#define FINF __builtin_huge_valf()

__device__ __forceinline__ float4 ld4s(const float* p) { return *(const float4*)p; }
__device__ __forceinline__ void st4s(float* p, float4 v) { *(float4*)p = v; }

// block-wide float sum; result valid in thread 0. sw = 4-entry shared scratch.
__device__ __forceinline__ float blockReduce(float v, float* sw) {
    #pragma unroll
    for (int o = 32; o; o >>= 1) v += __shfl_down(v, o, 64);
    int lane = threadIdx.x & 63, wid = threadIdx.x >> 6;
    if (lane == 0) sw[wid] = v;
    __syncthreads();
    float r = (threadIdx.x < 4) ? sw[threadIdx.x] : 0.f;
    if (wid == 0) { r += __shfl_down(r, 2, 64); r += __shfl_down(r, 1, 64); }
    __syncthreads();
    return r;
}

// ---------------------------------------------------------------- init
// acc: 48 doubles = per-image {sum_ep, sum_ep*y, sum_ep*x} for img 0..15
__global__ __launch_bounds__(64) void init_acc_kernel(double* acc) {
    int i = threadIdx.x;
    if (i < 48) acc[i] = 0.0;
}

// ---------------------------------------------------------------- phase 1
// softmax fg prob + y cast -> J0 (16 images). Dice partials -> pb[1024][3].
// No atomics (baseline's 83us was atomic-serialization on one cacheline).
__global__ __launch_bounds__(256) void phase1_kernel(
        const float* __restrict__ net, const int* __restrict__ yt,
        float* __restrict__ J0, double* __restrict__ pb) {
    __shared__ float sw[4];
    const int tid = threadIdx.x;
    float inter = 0.f, sp = 0.f, sy = 0.f;
    for (int i = blockIdx.x * 256 + tid; i < B * S / 4; i += 1024 * 256) {
        int b = i >> 16;               // S/4 = 65536 quads per image
        int s = (i & 65535) << 2;
        const float* nb = net + (size_t)b * 2 * S;
        float4 x0 = ld4s(nb + s);
        float4 x1 = ld4s(nb + S + s);
        int4 yv = *(const int4*)(yt + (size_t)b * S + s);
        float4 p, yf;
        p.x = 1.f / (1.f + expf(x0.x - x1.x));
        p.y = 1.f / (1.f + expf(x0.y - x1.y));
        p.z = 1.f / (1.f + expf(x0.z - x1.z));
        p.w = 1.f / (1.f + expf(x0.w - x1.w));
        yf.x = (float)yv.x; yf.y = (float)yv.y; yf.z = (float)yv.z; yf.w = (float)yv.w;
        st4s(J0 + (size_t)b * S + s, p);
        st4s(J0 + (size_t)(B + b) * S + s, yf);
        inter += p.x * yf.x + p.y * yf.y + p.z * yf.z + p.w * yf.w;
        sp += p.x + p.y + p.z + p.w;
        sy += yf.x + yf.y + yf.z + yf.w;
    }
    float v;
    v = blockReduce(inter, sw); if (tid == 0) pb[blockIdx.x * 3 + 0] = (double)v;
    v = blockReduce(sp, sw);    if (tid == 0) pb[blockIdx.x * 3 + 1] = (double)v;
    v = blockReduce(sy, sw);    if (tid == 0) pb[blockIdx.x * 3 + 2] = (double)v;
}

// ---------------------------------------------------------------- fused skeleton
// T rounds (rr = r0..5) per launch. Tile 88x88 double-buffered in LDS (62 KB),
// skel kept in registers (16 floats/thread). Per round:
//   E = erode(J) on shrinking region rows [1+2rr, 86-2rr], quad cols 0..87
//       (OOB-image cells forced to +inf so next erode's min ignores them)
//   D = dilate(E) at core (image-OOB taps predicated to -inf = zero... -inf pad)
//   delta = relu(J - D); skel += relu(delta - skel*delta); J <- E (LDS swap)
// Validity: erode quad edges (col 0/87) and stale-col creep advance 1 col/round
// while the needed region shrinks 2 cols/round -> never consumed.
template <bool INIT>
__global__ __launch_bounds__(256, 2) void skel_fused_kernel(
        const float* __restrict__ Jin, float* __restrict__ Jout,
        float* __restrict__ skel, int r0) {
    __shared__ float lds[2][LDT * LDT];
    const int tid = threadIdx.x;
    const int img = blockIdx.x >> 6;
    const int t64 = blockIdx.x & 63;
    const int ty = t64 >> 3, tx = t64 & 7;
    const int y0 = ty * CORE - HALO, x0 = tx * CORE - HALO;
    const float* Ji = Jin + (size_t)img * S;
    float* Jo = Jout + (size_t)img * S;
    float* Sk = skel + (size_t)img * S;
    const bool interior = (ty > 0) & (ty < 7) & (tx > 0) & (tx < 7);

    // ---- load 88x88 J tile (quads are all-in or all-out in x: x0 % 4 == 0)
    if (interior) {
        for (int i = tid; i < LDT * LDT / 4; i += 256) {
            int r = i / NQ, q = i - (i / NQ) * NQ;
            st4s(&lds[0][r * LDT + (q << 2)],
                 ld4s(Ji + (y0 + r) * W + x0 + (q << 2)));
        }
    } else {
        for (int i = tid; i < LDT * LDT / 4; i += 256) {
            int r = i / NQ, q = i - (i / NQ) * NQ;
            int gy = y0 + r, gx = x0 + (q << 2);
            float4 v;
            if ((unsigned)gy < H && (unsigned)gx < W) v = ld4s(Ji + gy * W + gx);
            else v = make_float4(FINF, FINF, FINF, FINF);
            st4s(&lds[0][r * LDT + (q << 2)], v);
        }
    }

    // ---- skel in registers: 4 quads/thread, qidx = k*256+tid,
    //      row = qidx>>4 (0..63), col = 4*(qidx&15)
    float4 sk[4];
    #pragma unroll
    for (int k = 0; k < 4; ++k) {
        if (INIT) {
            sk[k] = make_float4(0.f, 0.f, 0.f, 0.f);
        } else {
            int qidx = k * 256 + tid;
            int gy = ty * CORE + (qidx >> 4);
            int gx = tx * CORE + ((qidx & 15) << 2);
            sk[k] = ld4s(Sk + gy * W + gx);
        }
    }
    __syncthreads();

    int cur = 0;
    for (int rr = r0; rr < 6; ++rr) {
        const float* Jb = lds[cur];
        float* Eb = lds[cur ^ 1];

        // ---------------- erode (cross-min) ----------------
        const int rlo = 1 + 2 * rr;
        const int nit = (86 - 4 * rr) * NQ;
        for (int it = tid; it < nit; it += 256) {
            int rq = it / NQ;
            int q = it - rq * NQ;
            int r = rlo + rq;
            int c = q << 2;
            const float* Jr = Jb + r * LDT + c;
            float4 A  = ld4s(Jr);
            float4 U  = ld4s(Jr - LDT);
            float4 Dn = ld4s(Jr + LDT);
            float lw = (q > 0)      ? ld4s(Jr - 4).w : FINF;
            float rx = (q < NQ - 1) ? ld4s(Jr + 4).x : FINF;
            float m01 = fminf(A.x, A.y), m12 = fminf(A.y, A.z), m23 = fminf(A.z, A.w);
            float e0 = fminf(fminf(lw,  m01), fminf(U.x, Dn.x));
            float e1 = fminf(fminf(m01, A.z), fminf(U.y, Dn.y));
            float e2 = fminf(fminf(m12, A.w), fminf(U.z, Dn.z));
            float e3 = fminf(fminf(m23, rx),  fminf(U.w, Dn.w));
            if (!interior) {
                int gy = y0 + r, gx = x0 + c;
                if (!((unsigned)gy < H && (unsigned)gx < W)) {
                    e0 = FINF; e1 = FINF; e2 = FINF; e3 = FINF;
                }
            }
            st4s(&Eb[r * LDT + c], make_float4(e0, e1, e2, e3));
        }
        __syncthreads();

        // ---------------- dilate (3x3 max) + skel update ----------------
        const bool last = (rr == 5);
        #pragma unroll
        for (int k = 0; k < 4; ++k) {
            int qidx = k * 256 + tid;
            int row = qidx >> 4, colq = qidx & 15;
            int tr = HALO + row, tc = HALO + (colq << 2);
            const float* Ec = Eb + tr * LDT + tc;
            float4 c1 = ld4s(Ec);
            float4 m1 = ld4s(Ec - LDT);
            float4 p1 = ld4s(Ec + LDT);
            float lm_c = ld4s(Ec - 4).w,        rm_c = ld4s(Ec + 4).x;
            float lm_m = ld4s(Ec - LDT - 4).w,  rm_m = ld4s(Ec - LDT + 4).x;
            float lm_p = ld4s(Ec + LDT - 4).w,  rm_p = ld4s(Ec + LDT + 4).x;
            int gy = ty * CORE + row;
            int gx = tx * CORE + (colq << 2);
            if (!interior) {
                if (gx == 0)       { lm_c = -FINF; lm_m = -FINF; lm_p = -FINF; }
                if (gx + 4 == W)   { rm_c = -FINF; rm_m = -FINF; rm_p = -FINF; }
            }
            float am01 = fmaxf(m1.x, m1.y), am12 = fmaxf(m1.y, m1.z), am23 = fmaxf(m1.z, m1.w);
            float hm0 = fmaxf(lm_m, am01), hm1 = fmaxf(am01, m1.z);
            float hm2 = fmaxf(am12, m1.w), hm3 = fmaxf(am23, rm_m);
            float ac01 = fmaxf(c1.x, c1.y), ac12 = fmaxf(c1.y, c1.z), ac23 = fmaxf(c1.z, c1.w);
            float hc0 = fmaxf(lm_c, ac01), hc1 = fmaxf(ac01, c1.z);
            float hc2 = fmaxf(ac12, c1.w), hc3 = fmaxf(ac23, rm_c);
            float ap01 = fmaxf(p1.x, p1.y), ap12 = fmaxf(p1.y, p1.z), ap23 = fmaxf(p1.z, p1.w);
            float hp0 = fmaxf(lm_p, ap01), hp1 = fmaxf(ap01, p1.z);
            float hp2 = fmaxf(ap12, p1.w), hp3 = fmaxf(ap23, rm_p);
            if (!interior) {
                if (gy == 0)     { hm0 = -FINF; hm1 = -FINF; hm2 = -FINF; hm3 = -FINF; }
                if (gy == H - 1) { hp0 = -FINF; hp1 = -FINF; hp2 = -FINF; hp3 = -FINF; }
            }
            float d0 = fmaxf(fmaxf(hm0, hc0), hp0);
            float d1 = fmaxf(fmaxf(hm1, hc1), hp1);
            float d2 = fmaxf(fmaxf(hm2, hc2), hp2);
            float d3 = fmaxf(fmaxf(hm3, hc3), hp3);
            float4 J4 = ld4s(Jb + tr * LDT + tc);
            float dl0 = fmaxf(J4.x - d0, 0.f);
            float dl1 = fmaxf(J4.y - d1, 0.f);
            float dl2 = fmaxf(J4.z - d2, 0.f);
            float dl3 = fmaxf(J4.w - d3, 0.f);
            sk[k].x += fmaxf(dl0 - sk[k].x * dl0, 0.f);
            sk[k].y += fmaxf(dl1 - sk[k].y * dl1, 0.f);
            sk[k].z += fmaxf(dl2 - sk[k].z * dl2, 0.f);
            sk[k].w += fmaxf(dl3 - sk[k].w * dl3, 0.f);
            if (last) {
                st4s(Jo + gy * W + gx, c1);     // img_out = erode result at core
                st4s(Sk + gy * W + gx, sk[k]);
            }
        }
        if (!last) __syncthreads();
        cur ^= 1;
    }
}

// ---------------------------------------------------------------- endpoints
// ns = 3x3 zero-pad sum + 9*center; ep = exp(-(ns-11)^2)*skel.
// Block = 8 rows of one image, tiled in LDS with 1-row/1-col zero halo.
__global__ __launch_bounds__(256) void endpoint_kernel(
        const float* __restrict__ skel, double* __restrict__ acc) {
    __shared__ float sR[10][520];    // data at cols 4..515, zeros at 3 and 516
    __shared__ float sw[4];
    const int tid = threadIdx.x;
    const int img = blockIdx.x >> 6;
    const int rb = blockIdx.x & 63;
    const int yB = rb << 3;
    const float* Sk = skel + (size_t)img * S;
    for (int i = tid; i < 1280; i += 256) {
        int r = i >> 7, c4 = i & 127;
        int gy = yB - 1 + r;
        float4 v = make_float4(0.f, 0.f, 0.f, 0.f);
        if ((unsigned)gy < H) v = ld4s(Sk + gy * W + (c4 << 2));
        st4s(&sR[r][4 + (c4 << 2)], v);
    }
    if (tid < 10) { sR[tid][3] = 0.f; sR[tid][516] = 0.f; }
    __syncthreads();
    float t = 0.f, syA = 0.f, sxA = 0.f;
    #pragma unroll
    for (int k = 0; k < 4; ++k) {
        int qidx = k * 256 + tid;
        int rrow = qidx >> 7;            // 0..7
        int x = (qidx & 127) << 2;
        int r = 1 + rrow;
        float gy = (float)(yB + rrow);
        const float* Rm = &sR[r - 1][4 + x];
        const float* Rc = &sR[r][4 + x];
        const float* Rp = &sR[r + 1][4 + x];
        float4 bm = ld4s(Rm); float lm = ld4s(Rm - 4).w, rm = ld4s(Rm + 4).x;
        float4 bc = ld4s(Rc); float lc = ld4s(Rc - 4).w, rc = ld4s(Rc + 4).x;
        float4 bp = ld4s(Rp); float lp = ld4s(Rp - 4).w, rp = ld4s(Rp + 4).x;
        float hm0 = lm + bm.x + bm.y, hm1 = bm.x + bm.y + bm.z;
        float hm2 = bm.y + bm.z + bm.w, hm3 = bm.z + bm.w + rm;
        float hc0 = lc + bc.x + bc.y, hc1 = bc.x + bc.y + bc.z;
        float hc2 = bc.y + bc.z + bc.w, hc3 = bc.z + bc.w + rc;
        float hp0 = lp + bp.x + bp.y, hp1 = bp.x + bp.y + bp.z;
        float hp2 = bp.y + bp.z + bp.w, hp3 = bp.z + bp.w + rp;
        float ns0 = hm0 + hc0 + hp0 + 9.f * bc.x;
        float ns1 = hm1 + hc1 + hp1 + 9.f * bc.y;
        float ns2 = hm2 + hc2 + hp2 + 9.f * bc.z;
        float ns3 = hm3 + hc3 + hp3 + 9.f * bc.w;
        float e0 = ns0 - 11.f, e1 = ns1 - 11.f, e2 = ns2 - 11.f, e3 = ns3 - 11.f;
        float ep0 = expf(-e0 * e0) * bc.x;
        float ep1 = expf(-e1 * e1) * bc.y;
        float ep2 = expf(-e2 * e2) * bc.z;
        float ep3 = expf(-e3 * e3) * bc.w;
        float es = ep0 + ep1 + ep2 + ep3;
        t += es;
        syA += gy * es;
        sxA += ep0 * (float)(x + 0) + ep1 * (float)(x + 1)
             + ep2 * (float)(x + 2) + ep3 * (float)(x + 3);
    }
    float v;
    v = blockReduce(t, sw);   if (tid == 0) atomicAdd(&acc[img * 3 + 0], (double)v);
    v = blockReduce(syA, sw); if (tid == 0) atomicAdd(&acc[img * 3 + 1], (double)v);
    v = blockReduce(sxA, sw); if (tid == 0) atomicAdd(&acc[img * 3 + 2], (double)v);
}

// ---------------------------------------------------------------- final scalar
__global__ __launch_bounds__(256) void final_kernel(
        const double* __restrict__ acc, const double* __restrict__ pb,
        float* __restrict__ out) {
    const int tid = threadIdx.x;
    double si = 0.0, sp = 0.0, sy = 0.0;
    for (int i = tid; i < 1024; i += 256) {
        si += pb[i * 3 + 0]; sp += pb[i * 3 + 1]; sy += pb[i * 3 + 2];
    }
    #pragma unroll
    for (int o = 32; o; o >>= 1) {
        si += __shfl_down(si, o, 64);
        sp += __shfl_down(sp, o, 64);
        sy += __shfl_down(sy, o, 64);
    }
    __shared__ double dsw[3][4];
    int lane = tid & 63, wid = tid >> 6;
    if (lane == 0) { dsw[0][wid] = si; dsw[1][wid] = sp; dsw[2][wid] = sy; }
    __syncthreads();
    if (tid == 0) {
        double inter = dsw[0][0] + dsw[0][1] + dsw[0][2] + dsw[0][3];
        double sump  = dsw[1][0] + dsw[1][1] + dsw[1][2] + dsw[1][3];
        double sumy  = dsw[2][0] + dsw[2][1] + dsw[2][2] + dsw[2][3];
        double dsum = 0.0, csum = 0.0;
        for (int b = 0; b < B; ++b) {
            double tp = acc[b * 3 + 0], typ = acc[b * 3 + 1], txp = acc[b * 3 + 2];
            double tt = acc[(B + b) * 3 + 0], tyt = acc[(B + b) * 3 + 1], txt = acc[(B + b) * 3 + 2];
            double ycp = typ / (tp + 1e-8), xcp = txp / (tp + 1e-8);
            double yct = tyt / (tt + 1e-8), xct = txt / (tt + 1e-8);
            double dy = ycp - yct, dx = xcp - xct;
            dsum += sqrt(dy * dy + dx * dx);
            csum += fabs(tp - tt) / (tp + tt + 1e-8);
        }
        double diag = sqrt((double)(H * H + W * W));
        double distance_loss = (dsum / B) / (diag + 1e-8);
        double count_penalty = csum / B;
        double dice = 1.0 - (2.0 * inter + 1.0) / (sumy + sump + 1.0);
        out[0] = (float)(0.85 * dice + 0.15 * (distance_loss + count_penalty));
    }
}

// ---------------------------------------------------------------- launch
extern "C" void kernel_launch(void* const* d_in, const int* in_sizes, int n_in,
                              void* d_out, int out_size, void* d_ws, size_t ws_size,
                              hipStream_t stream) {
    const float* net = (const float*)d_in[0];   // [8,2,512,512] f32
    const int*   yt  = (const int*)d_in[1];     // [8,1,512,512] i32
    float* out = (float*)d_out;

    float* J0   = (float*)d_ws;                       // 16 MB
    float* J1   = J0 + (size_t)NIMG * S;              // 16 MB
    float* skel = J1 + (size_t)NIMG * S;              // 16 MB
    double* acc = (double*)(skel + (size_t)NIMG * S); // 48 doubles
    double* pb  = acc + 48;                           // 1024*3 doubles

    init_acc_kernel<<<1, 64, 0, stream>>>(acc);
    phase1_kernel<<<1024, 256, 0, stream>>>(net, yt, J0, pb);

    // 41 rounds = 6+6+6+6+6+6+5
    skel_fused_kernel<true><<<NIMG * 64, 256, 0, stream>>>(J0, J1, skel, 0);
    float* a = J1; float* b = J0;
    for (int p = 1; p < 7; ++p) {
        int r0 = (p == 6) ? 1 : 0;   // last phase: 5 rounds
        skel_fused_kernel<false><<<NIMG * 64, 256, 0, stream>>>(a, b, skel, r0);
        float* tmp = a; a = b; b = tmp;
    }

    endpoint_kernel<<<NIMG * 64, 256, 0, stream>>>(skel, acc);
    final_kernel<<<1, 256, 0, stream>>>(acc, pb, out);
}

// Round 3
// 425.505 us; speedup vs baseline: 2.3522x; 1.1205x over previous
//
#include <hip/hip_runtime.h>
#include <math.h>

#define W 512
#define H 512
#define S (W * H)        // 262144
#define B 8
#define NIMG 16
#define CORE 64
#define HALO 12
#define LDT 88           // tile width / row stride
#define LROWS 90         // 88 rows + 2 pad rows (register-window overread)
#define NQ 22            // quads per tile row
#define FINF __builtin_huge_valf()

__device__ __forceinline__ float4 ld4s(const float* p) { return *(const float4*)p; }
__device__ __forceinline__ void st4s(float* p, float4 v) { *(float4*)p = v; }

// block-wide float sum; result valid in thread 0. sw = 4-entry shared scratch.
__device__ __forceinline__ float blockReduce(float v, float* sw) {
    #pragma unroll
    for (int o = 32; o; o >>= 1) v += __shfl_down(v, o, 64);
    int lane = threadIdx.x & 63, wid = threadIdx.x >> 6;
    if (lane == 0) sw[wid] = v;
    __syncthreads();
    float r = (threadIdx.x < 4) ? sw[threadIdx.x] : 0.f;
    if (wid == 0) { r += __shfl_down(r, 2, 64); r += __shfl_down(r, 1, 64); }
    __syncthreads();
    return r;
}

// ---------------------------------------------------------------- init
// acc: 48 doubles = per-image {sum_ep, sum_ep*y, sum_ep*x} for img 0..15
__global__ __launch_bounds__(64) void init_acc_kernel(double* acc) {
    int i = threadIdx.x;
    if (i < 48) acc[i] = 0.0;
}

// ---------------------------------------------------------------- phase 1
__global__ __launch_bounds__(256) void phase1_kernel(
        const float* __restrict__ net, const int* __restrict__ yt,
        float* __restrict__ J0, double* __restrict__ pb) {
    __shared__ float sw[4];
    const int tid = threadIdx.x;
    float inter = 0.f, sp = 0.f, sy = 0.f;
    for (int i = blockIdx.x * 256 + tid; i < B * S / 4; i += 1024 * 256) {
        int b = i >> 16;               // S/4 = 65536 quads per image
        int s = (i & 65535) << 2;
        const float* nb = net + (size_t)b * 2 * S;
        float4 x0 = ld4s(nb + s);
        float4 x1 = ld4s(nb + S + s);
        int4 yv = *(const int4*)(yt + (size_t)b * S + s);
        float4 p, yf;
        p.x = 1.f / (1.f + expf(x0.x - x1.x));
        p.y = 1.f / (1.f + expf(x0.y - x1.y));
        p.z = 1.f / (1.f + expf(x0.z - x1.z));
        p.w = 1.f / (1.f + expf(x0.w - x1.w));
        yf.x = (float)yv.x; yf.y = (float)yv.y; yf.z = (float)yv.z; yf.w = (float)yv.w;
        st4s(J0 + (size_t)b * S + s, p);
        st4s(J0 + (size_t)(B + b) * S + s, yf);
        inter += p.x * yf.x + p.y * yf.y + p.z * yf.z + p.w * yf.w;
        sp += p.x + p.y + p.z + p.w;
        sy += yf.x + yf.y + yf.z + yf.w;
    }
    float v;
    v = blockReduce(inter, sw); if (tid == 0) pb[blockIdx.x * 3 + 0] = (double)v;
    v = blockReduce(sp, sw);    if (tid == 0) pb[blockIdx.x * 3 + 1] = (double)v;
    v = blockReduce(sy, sw);    if (tid == 0) pb[blockIdx.x * 3 + 2] = (double)v;
}

// ---------------------------------------------------------------- fused skeleton
// T=6 rounds per launch, 88x88 logical tile (90-row padded buffers, 62 KB).
// Per round: erode (cross-min, +inf OOB) over shrinking region; dilate (3x3
// max, -inf image pad) + delta + skel update at 64x64 core.
// NEW vs r2: each thread owns 4-row x 1-quad slabs with a 6-row register
// window (vertical neighbors from registers: 6 b128 reads -> 4 output rows),
// horizontal neighbors via wave shuffles (conflict-free) with LDS scalar
// fallback at wave-boundary lanes and -inf/+inf at tile/image edges.
template <bool INIT>
__global__ __launch_bounds__(256, 2) void skel_fused_kernel(
        const float* __restrict__ Jin, float* __restrict__ Jout,
        float* __restrict__ skel, int r0) {
    __shared__ float lds[2][LROWS * LDT];   // 2 x 90 x 88 floats = 63360 B
    const int tid = threadIdx.x;
    const int lane = tid & 63;
    const int img = blockIdx.x >> 6;
    const int t64 = blockIdx.x & 63;
    const int ty = t64 >> 3, tx = t64 & 7;
    const int y0 = ty * CORE - HALO, x0 = tx * CORE - HALO;
    const float* Ji = Jin + (size_t)img * S;
    float* Jo = Jout + (size_t)img * S;
    float* Sk = skel + (size_t)img * S;
    const bool interior = (ty > 0) & (ty < 7) & (tx > 0) & (tx < 7);

    // ---- load 88x88 J tile into lds[0] (quads all-in/out in x: x0 % 4 == 0)
    if (interior) {
        for (int i = tid; i < LDT * LDT / 4; i += 256) {
            int r = i / NQ, q = i - (i / NQ) * NQ;
            st4s(&lds[0][r * LDT + (q << 2)],
                 ld4s(Ji + (y0 + r) * W + x0 + (q << 2)));
        }
    } else {
        for (int i = tid; i < LDT * LDT / 4; i += 256) {
            int r = i / NQ, q = i - (i / NQ) * NQ;
            int gy = y0 + r, gx = x0 + (q << 2);
            float4 v;
            if ((unsigned)gy < H && (unsigned)gx < W) v = ld4s(Ji + gy * W + gx);
            else v = make_float4(FINF, FINF, FINF, FINF);
            st4s(&lds[0][r * LDT + (q << 2)], v);
        }
    }

    // ---- skel in registers: thread = slab (ss) rows 4ss..4ss+3, quad col sq
    const int sq = tid & 15, ss = tid >> 4;
    const int tcol = HALO + (sq << 2);          // tile col of core quad
    const int gxc = tx * CORE + (sq << 2);      // global col of core quad
    const int row0 = ss << 2;                   // core row offset of slab
    float4 sk4[4];
    #pragma unroll
    for (int j = 0; j < 4; ++j) {
        if (INIT) sk4[j] = make_float4(0.f, 0.f, 0.f, 0.f);
        else      sk4[j] = ld4s(Sk + (ty * CORE + row0 + j) * W + gxc);
    }
    __syncthreads();

    int cur = 0;
    for (int rr = r0; rr < 6; ++rr) {
        float* Jb = lds[cur];
        float* Eb = lds[cur ^ 1];
        const int rlo = 1 + 2 * rr, rhi = 86 - 2 * rr;
        const int qlo = rlo >> 2, qhi = rhi >> 2;
        const int nq = qhi - qlo + 1;
        const int nslab = (86 - 4 * rr + 3) >> 2;
        const int nit = nslab * nq;

        // ---------------- erode (cross-min), 4-row slabs ----------------
        for (int it = tid; it < nit; it += 256) {
            int sb = it / nq;
            int qq = qlo + (it - sb * nq);
            int rb = rlo + (sb << 2);
            int c = qq << 2;
            const float* basep = Jb + (rb - 1) * LDT + c;
            float4 wd[6];
            #pragma unroll
            for (int j = 0; j < 6; ++j) wd[j] = ld4s(basep + j * LDT);
            float lw[4], rx[4];
            #pragma unroll
            for (int j = 0; j < 4; ++j) {
                lw[j] = __shfl_up(wd[j + 1].w, 1, 64);
                rx[j] = __shfl_down(wd[j + 1].x, 1, 64);
                if (lane == 0 && qq != qlo) lw[j] = Jb[(rb + j) * LDT + c - 1];
                if (lane == 63 && qq != qhi) rx[j] = Jb[(rb + j) * LDT + c + 4];
                if (qq == qlo) lw[j] = FINF;   // tile-edge / creep col: safe
                if (qq == qhi) rx[j] = FINF;   // creep col: safe
            }
            bool cOOB = false;
            int gx = x0 + c;
            if (!interior) cOOB = ((unsigned)gx >= W);
            #pragma unroll
            for (int j = 0; j < 4; ++j) {
                int r = rb + j;
                float4 a = wd[j + 1], u = wd[j], dn = wd[j + 2];
                float4 e;
                e.x = fminf(fminf(fminf(u.x, dn.x), fminf(lw[j], a.y)), a.x);
                e.y = fminf(fminf(fminf(u.y, dn.y), fminf(a.x, a.z)), a.y);
                e.z = fminf(fminf(fminf(u.z, dn.z), fminf(a.y, a.w)), a.z);
                e.w = fminf(fminf(fminf(u.w, dn.w), fminf(a.z, rx[j])), a.w);
                if (!interior) {
                    int gy = y0 + r;
                    if (((unsigned)gy >= H) | cOOB)
                        e = make_float4(FINF, FINF, FINF, FINF);   // minpool pad
                }
                if (r <= rhi) st4s(&Eb[r * LDT + c], e);
            }
        }
        __syncthreads();

        // ------------- dilate (3x3 max) + delta + skel, one slab/thread -------------
        const bool last = (rr == 5);
        {
            const float* ebase = Eb + (row0 + 11) * LDT + tcol;
            float4 E[6];
            #pragma unroll
            for (int j = 0; j < 6; ++j) E[j] = ld4s(ebase + j * LDT);
            float lwv[6], rxv[6];
            #pragma unroll
            for (int j = 0; j < 6; ++j) {
                lwv[j] = __shfl_up(E[j].w, 1, 64);    // sq==0 <=> lane%16==0 handled below
                rxv[j] = __shfl_down(E[j].x, 1, 64);
                if (sq == 0)  lwv[j] = (tx == 0) ? -FINF : Eb[(row0 + 11 + j) * LDT + 11];
                if (sq == 15) rxv[j] = (tx == 7) ? -FINF : Eb[(row0 + 11 + j) * LDT + 76];
            }
            float4 hx[6];
            #pragma unroll
            for (int j = 0; j < 6; ++j) {
                hx[j].x = fmaxf(fmaxf(lwv[j], E[j].x), E[j].y);
                hx[j].y = fmaxf(fmaxf(E[j].x, E[j].y), E[j].z);
                hx[j].z = fmaxf(fmaxf(E[j].y, E[j].z), E[j].w);
                hx[j].w = fmaxf(fmaxf(E[j].z, E[j].w), rxv[j]);
            }
            #pragma unroll
            for (int j = 0; j < 4; ++j) {
                int gy = ty * CORE + row0 + j;
                float4 hm = hx[j], hp = hx[j + 2];
                if (!interior) {
                    if (gy == 0)     hm = make_float4(-FINF, -FINF, -FINF, -FINF);
                    if (gy == H - 1) hp = make_float4(-FINF, -FINF, -FINF, -FINF);
                }
                float4 dm;
                dm.x = fmaxf(fmaxf(hm.x, hx[j + 1].x), hp.x);
                dm.y = fmaxf(fmaxf(hm.y, hx[j + 1].y), hp.y);
                dm.z = fmaxf(fmaxf(hm.z, hx[j + 1].z), hp.z);
                dm.w = fmaxf(fmaxf(hm.w, hx[j + 1].w), hp.w);
                float4 Jv = ld4s(Jb + (row0 + 12 + j) * LDT + tcol);
                float d0 = fmaxf(Jv.x - dm.x, 0.f);
                float d1 = fmaxf(Jv.y - dm.y, 0.f);
                float d2 = fmaxf(Jv.z - dm.z, 0.f);
                float d3 = fmaxf(Jv.w - dm.w, 0.f);
                sk4[j].x += fmaxf(d0 - sk4[j].x * d0, 0.f);
                sk4[j].y += fmaxf(d1 - sk4[j].y * d1, 0.f);
                sk4[j].z += fmaxf(d2 - sk4[j].z * d2, 0.f);
                sk4[j].w += fmaxf(d3 - sk4[j].w * d3, 0.f);
                if (last) {
                    st4s(Jo + gy * W + gxc, E[j + 1]);   // Jout = erode result
                    st4s(Sk + gy * W + gxc, sk4[j]);
                }
            }
        }
        if (!last) __syncthreads();
        cur ^= 1;
    }
}

// ---------------------------------------------------------------- endpoints
__global__ __launch_bounds__(256) void endpoint_kernel(
        const float* __restrict__ skel, double* __restrict__ acc) {
    __shared__ float sR[10][520];    // data at cols 4..515, zeros at 3 and 516
    __shared__ float sw[4];
    const int tid = threadIdx.x;
    const int img = blockIdx.x >> 6;
    const int rb = blockIdx.x & 63;
    const int yB = rb << 3;
    const float* Sk = skel + (size_t)img * S;
    for (int i = tid; i < 1280; i += 256) {
        int r = i >> 7, c4 = i & 127;
        int gy = yB - 1 + r;
        float4 v = make_float4(0.f, 0.f, 0.f, 0.f);
        if ((unsigned)gy < H) v = ld4s(Sk + gy * W + (c4 << 2));
        st4s(&sR[r][4 + (c4 << 2)], v);
    }
    if (tid < 10) { sR[tid][3] = 0.f; sR[tid][516] = 0.f; }
    __syncthreads();
    float t = 0.f, syA = 0.f, sxA = 0.f;
    #pragma unroll
    for (int k = 0; k < 4; ++k) {
        int qidx = k * 256 + tid;
        int rrow = qidx >> 7;            // 0..7
        int x = (qidx & 127) << 2;
        int r = 1 + rrow;
        float gy = (float)(yB + rrow);
        const float* Rm = &sR[r - 1][4 + x];
        const float* Rc = &sR[r][4 + x];
        const float* Rp = &sR[r + 1][4 + x];
        float4 bm = ld4s(Rm); float lm = ld4s(Rm - 4).w, rm = ld4s(Rm + 4).x;
        float4 bc = ld4s(Rc); float lc = ld4s(Rc - 4).w, rc = ld4s(Rc + 4).x;
        float4 bp = ld4s(Rp); float lp = ld4s(Rp - 4).w, rp = ld4s(Rp + 4).x;
        float hm0 = lm + bm.x + bm.y, hm1 = bm.x + bm.y + bm.z;
        float hm2 = bm.y + bm.z + bm.w, hm3 = bm.z + bm.w + rm;
        float hc0 = lc + bc.x + bc.y, hc1 = bc.x + bc.y + bc.z;
        float hc2 = bc.y + bc.z + bc.w, hc3 = bc.z + bc.w + rc;
        float hp0 = lp + bp.x + bp.y, hp1 = bp.x + bp.y + bp.z;
        float hp2 = bp.y + bp.z + bp.w, hp3 = bp.z + bp.w + rp;
        float ns0 = hm0 + hc0 + hp0 + 9.f * bc.x;
        float ns1 = hm1 + hc1 + hp1 + 9.f * bc.y;
        float ns2 = hm2 + hc2 + hp2 + 9.f * bc.z;
        float ns3 = hm3 + hc3 + hp3 + 9.f * bc.w;
        float e0 = ns0 - 11.f, e1 = ns1 - 11.f, e2 = ns2 - 11.f, e3 = ns3 - 11.f;
        float ep0 = expf(-e0 * e0) * bc.x;
        float ep1 = expf(-e1 * e1) * bc.y;
        float ep2 = expf(-e2 * e2) * bc.z;
        float ep3 = expf(-e3 * e3) * bc.w;
        float es = ep0 + ep1 + ep2 + ep3;
        t += es;
        syA += gy * es;
        sxA += ep0 * (float)(x + 0) + ep1 * (float)(x + 1)
             + ep2 * (float)(x + 2) + ep3 * (float)(x + 3);
    }
    float v;
    v = blockReduce(t, sw);   if (tid == 0) atomicAdd(&acc[img * 3 + 0], (double)v);
    v = blockReduce(syA, sw); if (tid == 0) atomicAdd(&acc[img * 3 + 1], (double)v);
    v = blockReduce(sxA, sw); if (tid == 0) atomicAdd(&acc[img * 3 + 2], (double)v);
}

// ---------------------------------------------------------------- final scalar
__global__ __launch_bounds__(256) void final_kernel(
        const double* __restrict__ acc, const double* __restrict__ pb,
        float* __restrict__ out) {
    const int tid = threadIdx.x;
    double si = 0.0, sp = 0.0, sy = 0.0;
    for (int i = tid; i < 1024; i += 256) {
        si += pb[i * 3 + 0]; sp += pb[i * 3 + 1]; sy += pb[i * 3 + 2];
    }
    #pragma unroll
    for (int o = 32; o; o >>= 1) {
        si += __shfl_down(si, o, 64);
        sp += __shfl_down(sp, o, 64);
        sy += __shfl_down(sy, o, 64);
    }
    __shared__ double dsw[3][4];
    int lane = tid & 63, wid = tid >> 6;
    if (lane == 0) { dsw[0][wid] = si; dsw[1][wid] = sp; dsw[2][wid] = sy; }
    __syncthreads();
    if (tid == 0) {
        double inter = dsw[0][0] + dsw[0][1] + dsw[0][2] + dsw[0][3];
        double sump  = dsw[1][0] + dsw[1][1] + dsw[1][2] + dsw[1][3];
        double sumy  = dsw[2][0] + dsw[2][1] + dsw[2][2] + dsw[2][3];
        double dsum = 0.0, csum = 0.0;
        for (int b = 0; b < B; ++b) {
            double tp = acc[b * 3 + 0], typ = acc[b * 3 + 1], txp = acc[b * 3 + 2];
            double tt = acc[(B + b) * 3 + 0], tyt = acc[(B + b) * 3 + 1], txt = acc[(B + b) * 3 + 2];
            double ycp = typ / (tp + 1e-8), xcp = txp / (tp + 1e-8);
            double yct = tyt / (tt + 1e-8), xct = txt / (tt + 1e-8);
            double dy = ycp - yct, dx = xcp - xct;
            dsum += sqrt(dy * dy + dx * dx);
            csum += fabs(tp - tt) / (tp + tt + 1e-8);
        }
        double diag = sqrt((double)(H * H + W * W));
        double distance_loss = (dsum / B) / (diag + 1e-8);
        double count_penalty = csum / B;
        double dice = 1.0 - (2.0 * inter + 1.0) / (sumy + sump + 1.0);
        out[0] = (float)(0.85 * dice + 0.15 * (distance_loss + count_penalty));
    }
}

// ---------------------------------------------------------------- launch
extern "C" void kernel_launch(void* const* d_in, const int* in_sizes, int n_in,
                              void* d_out, int out_size, void* d_ws, size_t ws_size,
                              hipStream_t stream) {
    const float* net = (const float*)d_in[0];   // [8,2,512,512] f32
    const int*   yt  = (const int*)d_in[1];     // [8,1,512,512] i32
    float* out = (float*)d_out;

    float* J0   = (float*)d_ws;                       // 16 MB
    float* J1   = J0 + (size_t)NIMG * S;              // 16 MB
    float* skel = J1 + (size_t)NIMG * S;              // 16 MB
    double* acc = (double*)(skel + (size_t)NIMG * S); // 48 doubles
    double* pb  = acc + 48;                           // 1024*3 doubles

    init_acc_kernel<<<1, 64, 0, stream>>>(acc);
    phase1_kernel<<<1024, 256, 0, stream>>>(net, yt, J0, pb);

    // 41 rounds = 6+6+6+6+6+6+5
    skel_fused_kernel<true><<<NIMG * 64, 256, 0, stream>>>(J0, J1, skel, 0);
    float* a = J1; float* b = J0;
    for (int p = 1; p < 7; ++p) {
        int r0 = (p == 6) ? 1 : 0;   // last phase: 5 rounds (rr = 1..5)
        skel_fused_kernel<false><<<NIMG * 64, 256, 0, stream>>>(a, b, skel, r0);
        float* tmp = a; a = b; b = tmp;
    }

    endpoint_kernel<<<NIMG * 64, 256, 0, stream>>>(skel, acc);
    final_kernel<<<1, 256, 0, stream>>>(acc, pb, out);
}

// Round 4
// 368.992 us; speedup vs baseline: 2.7125x; 1.1532x over previous
//
#include <hip/hip_runtime.h>
#include <math.h>

#define W 512
#define H 512
#define S (W * H)        // 262144
#define B 8
#define NIMG 16
#define CORE 64
#define HALO 12
#define LDT 88           // tile width / row stride
#define LROWS 90         // 88 rows + 2 pad rows (register-window overread)
#define NQ 22            // quads per tile row
#define FINF __builtin_huge_valf()

__device__ __forceinline__ float4 ld4s(const float* p) { return *(const float4*)p; }
__device__ __forceinline__ void st4s(float* p, float4 v) { *(float4*)p = v; }

// block-wide float sum over 256 threads; result valid in thread 0.
__device__ __forceinline__ float blockReduce(float v, float* sw) {
    #pragma unroll
    for (int o = 32; o; o >>= 1) v += __shfl_down(v, o, 64);
    int lane = threadIdx.x & 63, wid = threadIdx.x >> 6;
    if (lane == 0) sw[wid] = v;
    __syncthreads();
    float r = (threadIdx.x < 4) ? sw[threadIdx.x] : 0.f;
    if (wid == 0) { r += __shfl_down(r, 2, 64); r += __shfl_down(r, 1, 64); }
    __syncthreads();
    return r;
}

// ---------------------------------------------------------------- phase 1
// softmax fg prob + y cast -> J0; dice partials -> pb; block 0 zeros acc.
__global__ __launch_bounds__(256) void phase1_kernel(
        const float* __restrict__ net, const int* __restrict__ yt,
        float* __restrict__ J0, double* __restrict__ pb,
        double* __restrict__ acc) {
    __shared__ float sw[4];
    const int tid = threadIdx.x;
    if (blockIdx.x == 0 && tid < 48) acc[tid] = 0.0;   // endpoint accumulators
    float inter = 0.f, sp = 0.f, sy = 0.f;
    for (int i = blockIdx.x * 256 + tid; i < B * S / 4; i += 1024 * 256) {
        int b = i >> 16;               // S/4 = 65536 quads per image
        int s = (i & 65535) << 2;
        const float* nb = net + (size_t)b * 2 * S;
        float4 x0 = ld4s(nb + s);
        float4 x1 = ld4s(nb + S + s);
        int4 yv = *(const int4*)(yt + (size_t)b * S + s);
        float4 p, yf;
        p.x = 1.f / (1.f + expf(x0.x - x1.x));
        p.y = 1.f / (1.f + expf(x0.y - x1.y));
        p.z = 1.f / (1.f + expf(x0.z - x1.z));
        p.w = 1.f / (1.f + expf(x0.w - x1.w));
        yf.x = (float)yv.x; yf.y = (float)yv.y; yf.z = (float)yv.z; yf.w = (float)yv.w;
        st4s(J0 + (size_t)b * S + s, p);
        st4s(J0 + (size_t)(B + b) * S + s, yf);
        inter += p.x * yf.x + p.y * yf.y + p.z * yf.z + p.w * yf.w;
        sp += p.x + p.y + p.z + p.w;
        sy += yf.x + yf.y + yf.z + yf.w;
    }
    float v;
    v = blockReduce(inter, sw); if (tid == 0) pb[blockIdx.x * 3 + 0] = (double)v;
    v = blockReduce(sp, sw);    if (tid == 0) pb[blockIdx.x * 3 + 1] = (double)v;
    v = blockReduce(sy, sw);    if (tid == 0) pb[blockIdx.x * 3 + 2] = (double)v;
}

// ---------------------------------------------------------------- fused skeleton
// T=6 rounds per launch, 88x88 logical tile (90-row padded buffers, 62 KB).
// 512 threads / 8 waves per block: 2 blocks/CU -> 16 waves/CU (50% cap) for
// latency hiding on the DS pipe (r3 was 25%-capped: 256 thr, 17% measured).
// erode: 4-row x 1-quad slabs, 484 units, single sweep.
// dilate: 2-row x 1-quad slabs, 512 units, one per thread; skel in registers.
template <bool INIT>
__global__ __launch_bounds__(512, 4) void skel_fused_kernel(
        const float* __restrict__ Jin, float* __restrict__ Jout,
        float* __restrict__ skel, int r0) {
    __shared__ float lds[2][LROWS * LDT];   // 2 x 90 x 88 floats = 63360 B
    const int tid = threadIdx.x;
    const int lane = tid & 63;
    const int img = blockIdx.x >> 6;
    const int t64 = blockIdx.x & 63;
    const int ty = t64 >> 3, tx = t64 & 7;
    const int y0 = ty * CORE - HALO, x0 = tx * CORE - HALO;
    const float* Ji = Jin + (size_t)img * S;
    float* Jo = Jout + (size_t)img * S;
    float* Sk = skel + (size_t)img * S;
    const bool interior = (ty > 0) & (ty < 7) & (tx > 0) & (tx < 7);

    // ---- load 88x88 J tile into lds[0] (quads all-in/out in x: x0 % 4 == 0)
    if (interior) {
        for (int i = tid; i < LDT * LDT / 4; i += 512) {
            int r = i / NQ, q = i - (i / NQ) * NQ;
            st4s(&lds[0][r * LDT + (q << 2)],
                 ld4s(Ji + (y0 + r) * W + x0 + (q << 2)));
        }
    } else {
        for (int i = tid; i < LDT * LDT / 4; i += 512) {
            int r = i / NQ, q = i - (i / NQ) * NQ;
            int gy = y0 + r, gx = x0 + (q << 2);
            float4 v;
            if ((unsigned)gy < H && (unsigned)gx < W) v = ld4s(Ji + gy * W + gx);
            else v = make_float4(FINF, FINF, FINF, FINF);
            st4s(&lds[0][r * LDT + (q << 2)], v);
        }
    }

    // ---- skel in registers: thread = 2-row slab, rows {2ss, 2ss+1}, quad sq
    const int sq = tid & 15, ss = tid >> 4;     // sq 0..15, ss 0..31
    const int tcol = HALO + (sq << 2);          // tile col of core quad
    const int gxc = tx * CORE + (sq << 2);      // global col of core quad
    const int row0 = ss << 1;                   // core row offset of slab
    float4 sk2[2];
    #pragma unroll
    for (int j = 0; j < 2; ++j) {
        if (INIT) sk2[j] = make_float4(0.f, 0.f, 0.f, 0.f);
        else      sk2[j] = ld4s(Sk + (ty * CORE + row0 + j) * W + gxc);
    }
    __syncthreads();

    int cur = 0;
    for (int rr = r0; rr < 6; ++rr) {
        float* Jb = lds[cur];
        float* Eb = lds[cur ^ 1];
        const int rlo = 1 + 2 * rr, rhi = 86 - 2 * rr;
        const int qlo = rlo >> 2, qhi = rhi >> 2;
        const int nq = qhi - qlo + 1;
        const int nslab = (rhi - rlo + 1 + 3) >> 2;
        const int nit = nslab * nq;             // <= 484 always

        // -------- erode (cross-min), 4-row slabs, single sweep --------
        if (tid < nit) {
            int sb = tid / nq;
            int qq = qlo + (tid - sb * nq);
            int rb = rlo + (sb << 2);
            int c = qq << 2;
            const float* basep = Jb + (rb - 1) * LDT + c;
            float4 wd[6];
            #pragma unroll
            for (int j = 0; j < 6; ++j) wd[j] = ld4s(basep + j * LDT);
            float lw[4], rx[4];
            #pragma unroll
            for (int j = 0; j < 4; ++j) {
                lw[j] = __shfl_up(wd[j + 1].w, 1, 64);
                rx[j] = __shfl_down(wd[j + 1].x, 1, 64);
                if (lane == 0 && qq != qlo) lw[j] = Jb[(rb + j) * LDT + c - 1];
                if (lane == 63 && qq != qhi) rx[j] = Jb[(rb + j) * LDT + c + 4];
                if (qq == qlo) lw[j] = FINF;   // tile-edge / creep col: safe
                if (qq == qhi) rx[j] = FINF;   // creep col: safe
            }
            bool cOOB = false;
            int gx = x0 + c;
            if (!interior) cOOB = ((unsigned)gx >= W);
            #pragma unroll
            for (int j = 0; j < 4; ++j) {
                int r = rb + j;
                float4 a = wd[j + 1], u = wd[j], dn = wd[j + 2];
                float4 e;
                e.x = fminf(fminf(fminf(u.x, dn.x), fminf(lw[j], a.y)), a.x);
                e.y = fminf(fminf(fminf(u.y, dn.y), fminf(a.x, a.z)), a.y);
                e.z = fminf(fminf(fminf(u.z, dn.z), fminf(a.y, a.w)), a.z);
                e.w = fminf(fminf(fminf(u.w, dn.w), fminf(a.z, rx[j])), a.w);
                if (!interior) {
                    int gy = y0 + r;
                    if (((unsigned)gy >= H) | cOOB)
                        e = make_float4(FINF, FINF, FINF, FINF);   // minpool pad
                }
                if (r <= rhi) st4s(&Eb[r * LDT + c], e);
            }
        }
        __syncthreads();

        // ------- dilate (3x3 max) + delta + skel, 2-row slab per thread -------
        const bool last = (rr == 5);
        {
            const float* ebase = Eb + (row0 + 11) * LDT + tcol;
            float4 E[4];
            #pragma unroll
            for (int j = 0; j < 4; ++j) E[j] = ld4s(ebase + j * LDT);
            float lwv[4], rxv[4];
            #pragma unroll
            for (int j = 0; j < 4; ++j) {
                lwv[j] = __shfl_up(E[j].w, 1, 64);
                rxv[j] = __shfl_down(E[j].x, 1, 64);
                if (sq == 0)  lwv[j] = (tx == 0) ? -FINF : Eb[(row0 + 11 + j) * LDT + 11];
                if (sq == 15) rxv[j] = (tx == 7) ? -FINF : Eb[(row0 + 11 + j) * LDT + 76];
            }
            float4 hx[4];
            #pragma unroll
            for (int j = 0; j < 4; ++j) {
                hx[j].x = fmaxf(fmaxf(lwv[j], E[j].x), E[j].y);
                hx[j].y = fmaxf(fmaxf(E[j].x, E[j].y), E[j].z);
                hx[j].z = fmaxf(fmaxf(E[j].y, E[j].z), E[j].w);
                hx[j].w = fmaxf(fmaxf(E[j].z, E[j].w), rxv[j]);
            }
            #pragma unroll
            for (int j = 0; j < 2; ++j) {
                int gy = ty * CORE + row0 + j;
                float4 hm = hx[j], hp = hx[j + 2];
                if (!interior) {
                    if (gy == 0)     hm = make_float4(-FINF, -FINF, -FINF, -FINF);
                    if (gy == H - 1) hp = make_float4(-FINF, -FINF, -FINF, -FINF);
                }
                float4 dm;
                dm.x = fmaxf(fmaxf(hm.x, hx[j + 1].x), hp.x);
                dm.y = fmaxf(fmaxf(hm.y, hx[j + 1].y), hp.y);
                dm.z = fmaxf(fmaxf(hm.z, hx[j + 1].z), hp.z);
                dm.w = fmaxf(fmaxf(hm.w, hx[j + 1].w), hp.w);
                float4 Jv = ld4s(Jb + (row0 + 12 + j) * LDT + tcol);
                float d0 = fmaxf(Jv.x - dm.x, 0.f);
                float d1 = fmaxf(Jv.y - dm.y, 0.f);
                float d2 = fmaxf(Jv.z - dm.z, 0.f);
                float d3 = fmaxf(Jv.w - dm.w, 0.f);
                sk2[j].x += fmaxf(d0 - sk2[j].x * d0, 0.f);
                sk2[j].y += fmaxf(d1 - sk2[j].y * d1, 0.f);
                sk2[j].z += fmaxf(d2 - sk2[j].z * d2, 0.f);
                sk2[j].w += fmaxf(d3 - sk2[j].w * d3, 0.f);
                if (last) {
                    st4s(Jo + gy * W + gxc, E[j + 1]);   // Jout = erode at core
                    st4s(Sk + gy * W + gxc, sk2[j]);
                }
            }
        }
        if (!last) __syncthreads();
        cur ^= 1;
    }
}

// ---------------------------------------------------------------- endpoints
__global__ __launch_bounds__(256) void endpoint_kernel(
        const float* __restrict__ skel, double* __restrict__ acc) {
    __shared__ float sR[10][520];    // data at cols 4..515, zeros at 3 and 516
    __shared__ float sw[4];
    const int tid = threadIdx.x;
    const int img = blockIdx.x >> 6;
    const int rb = blockIdx.x & 63;
    const int yB = rb << 3;
    const float* Sk = skel + (size_t)img * S;
    for (int i = tid; i < 1280; i += 256) {
        int r = i >> 7, c4 = i & 127;
        int gy = yB - 1 + r;
        float4 v = make_float4(0.f, 0.f, 0.f, 0.f);
        if ((unsigned)gy < H) v = ld4s(Sk + gy * W + (c4 << 2));
        st4s(&sR[r][4 + (c4 << 2)], v);
    }
    if (tid < 10) { sR[tid][3] = 0.f; sR[tid][516] = 0.f; }
    __syncthreads();
    float t = 0.f, syA = 0.f, sxA = 0.f;
    #pragma unroll
    for (int k = 0; k < 4; ++k) {
        int qidx = k * 256 + tid;
        int rrow = qidx >> 7;            // 0..7
        int x = (qidx & 127) << 2;
        int r = 1 + rrow;
        float gy = (float)(yB + rrow);
        const float* Rm = &sR[r - 1][4 + x];
        const float* Rc = &sR[r][4 + x];
        const float* Rp = &sR[r + 1][4 + x];
        float4 bm = ld4s(Rm); float lm = ld4s(Rm - 4).w, rm = ld4s(Rm + 4).x;
        float4 bc = ld4s(Rc); float lc = ld4s(Rc - 4).w, rc = ld4s(Rc + 4).x;
        float4 bp = ld4s(Rp); float lp = ld4s(Rp - 4).w, rp = ld4s(Rp + 4).x;
        float hm0 = lm + bm.x + bm.y, hm1 = bm.x + bm.y + bm.z;
        float hm2 = bm.y + bm.z + bm.w, hm3 = bm.z + bm.w + rm;
        float hc0 = lc + bc.x + bc.y, hc1 = bc.x + bc.y + bc.z;
        float hc2 = bc.y + bc.z + bc.w, hc3 = bc.z + bc.w + rc;
        float hp0 = lp + bp.x + bp.y, hp1 = bp.x + bp.y + bp.z;
        float hp2 = bp.y + bp.z + bp.w, hp3 = bp.z + bp.w + rp;
        float ns0 = hm0 + hc0 + hp0 + 9.f * bc.x;
        float ns1 = hm1 + hc1 + hp1 + 9.f * bc.y;
        float ns2 = hm2 + hc2 + hp2 + 9.f * bc.z;
        float ns3 = hm3 + hc3 + hp3 + 9.f * bc.w;
        float e0 = ns0 - 11.f, e1 = ns1 - 11.f, e2 = ns2 - 11.f, e3 = ns3 - 11.f;
        float ep0 = expf(-e0 * e0) * bc.x;
        float ep1 = expf(-e1 * e1) * bc.y;
        float ep2 = expf(-e2 * e2) * bc.z;
        float ep3 = expf(-e3 * e3) * bc.w;
        float es = ep0 + ep1 + ep2 + ep3;
        t += es;
        syA += gy * es;
        sxA += ep0 * (float)(x + 0) + ep1 * (float)(x + 1)
             + ep2 * (float)(x + 2) + ep3 * (float)(x + 3);
    }
    float v;
    v = blockReduce(t, sw);   if (tid == 0) atomicAdd(&acc[img * 3 + 0], (double)v);
    v = blockReduce(syA, sw); if (tid == 0) atomicAdd(&acc[img * 3 + 1], (double)v);
    v = blockReduce(sxA, sw); if (tid == 0) atomicAdd(&acc[img * 3 + 2], (double)v);
}

// ---------------------------------------------------------------- final scalar
__global__ __launch_bounds__(256) void final_kernel(
        const double* __restrict__ acc, const double* __restrict__ pb,
        float* __restrict__ out) {
    const int tid = threadIdx.x;
    double si = 0.0, sp = 0.0, sy = 0.0;
    for (int i = tid; i < 1024; i += 256) {
        si += pb[i * 3 + 0]; sp += pb[i * 3 + 1]; sy += pb[i * 3 + 2];
    }
    #pragma unroll
    for (int o = 32; o; o >>= 1) {
        si += __shfl_down(si, o, 64);
        sp += __shfl_down(sp, o, 64);
        sy += __shfl_down(sy, o, 64);
    }
    __shared__ double dsw[3][4];
    int lane = tid & 63, wid = tid >> 6;
    if (lane == 0) { dsw[0][wid] = si; dsw[1][wid] = sp; dsw[2][wid] = sy; }
    __syncthreads();
    if (tid == 0) {
        double inter = dsw[0][0] + dsw[0][1] + dsw[0][2] + dsw[0][3];
        double sump  = dsw[1][0] + dsw[1][1] + dsw[1][2] + dsw[1][3];
        double sumy  = dsw[2][0] + dsw[2][1] + dsw[2][2] + dsw[2][3];
        double dsum = 0.0, csum = 0.0;
        for (int b = 0; b < B; ++b) {
            double tp = acc[b * 3 + 0], typ = acc[b * 3 + 1], txp = acc[b * 3 + 2];
            double tt = acc[(B + b) * 3 + 0], tyt = acc[(B + b) * 3 + 1], txt = acc[(B + b) * 3 + 2];
            double ycp = typ / (tp + 1e-8), xcp = txp / (tp + 1e-8);
            double yct = tyt / (tt + 1e-8), xct = txt / (tt + 1e-8);
            double dy = ycp - yct, dx = xcp - xct;
            dsum += sqrt(dy * dy + dx * dx);
            csum += fabs(tp - tt) / (tp + tt + 1e-8);
        }
        double diag = sqrt((double)(H * H + W * W));
        double distance_loss = (dsum / B) / (diag + 1e-8);
        double count_penalty = csum / B;
        double dice = 1.0 - (2.0 * inter + 1.0) / (sumy + sump + 1.0);
        out[0] = (float)(0.85 * dice + 0.15 * (distance_loss + count_penalty));
    }
}

// ---------------------------------------------------------------- launch
extern "C" void kernel_launch(void* const* d_in, const int* in_sizes, int n_in,
                              void* d_out, int out_size, void* d_ws, size_t ws_size,
                              hipStream_t stream) {
    const float* net = (const float*)d_in[0];   // [8,2,512,512] f32
    const int*   yt  = (const int*)d_in[1];     // [8,1,512,512] i32
    float* out = (float*)d_out;

    float* J0   = (float*)d_ws;                       // 16 MB
    float* J1   = J0 + (size_t)NIMG * S;              // 16 MB
    float* skel = J1 + (size_t)NIMG * S;              // 16 MB
    double* acc = (double*)(skel + (size_t)NIMG * S); // 48 doubles
    double* pb  = acc + 48;                           // 1024*3 doubles

    phase1_kernel<<<1024, 256, 0, stream>>>(net, yt, J0, pb, acc);

    // 41 rounds = 6+6+6+6+6+6+5
    skel_fused_kernel<true><<<NIMG * 64, 512, 0, stream>>>(J0, J1, skel, 0);
    float* a = J1; float* b = J0;
    for (int p = 1; p < 7; ++p) {
        int r0 = (p == 6) ? 1 : 0;   // last phase: 5 rounds (rr = 1..5)
        skel_fused_kernel<false><<<NIMG * 64, 512, 0, stream>>>(a, b, skel, r0);
        float* tmp = a; a = b; b = tmp;
    }

    endpoint_kernel<<<NIMG * 64, 256, 0, stream>>>(skel, acc);
    final_kernel<<<1, 256, 0, stream>>>(acc, pb, out);
}

// Round 5
// 344.658 us; speedup vs baseline: 2.9040x; 1.0706x over previous
//
#include <hip/hip_runtime.h>
#include <math.h>

#define W 512
#define H 512
#define S (W * H)        // 262144
#define B 8
#define NIMG 16
#define CORE 64
#define HALO 12
#define LDT 88           // tile width / row stride
#define LROWS 90         // 88 rows + 2 pad rows (register-window overread)
#define NQ 22            // quads per tile row
#define FINF __builtin_huge_valf()

__device__ __forceinline__ float4 ld4s(const float* p) { return *(const float4*)p; }
__device__ __forceinline__ void st4s(float* p, float4 v) { *(float4*)p = v; }

// block-wide float sum over 256 threads; result valid in thread 0.
__device__ __forceinline__ float blockReduce(float v, float* sw) {
    #pragma unroll
    for (int o = 32; o; o >>= 1) v += __shfl_down(v, o, 64);
    int lane = threadIdx.x & 63, wid = threadIdx.x >> 6;
    if (lane == 0) sw[wid] = v;
    __syncthreads();
    float r = (threadIdx.x < 4) ? sw[threadIdx.x] : 0.f;
    if (wid == 0) { r += __shfl_down(r, 2, 64); r += __shfl_down(r, 1, 64); }
    __syncthreads();
    return r;
}

// ---------------------------------------------------------------- phase 1
// softmax fg prob + y cast -> J0; dice partials -> pb; block 0 zeros acc.
__global__ __launch_bounds__(256) void phase1_kernel(
        const float* __restrict__ net, const int* __restrict__ yt,
        float* __restrict__ J0, double* __restrict__ pb,
        double* __restrict__ acc) {
    __shared__ float sw[4];
    const int tid = threadIdx.x;
    if (blockIdx.x == 0 && tid < 48) acc[tid] = 0.0;   // endpoint accumulators
    float inter = 0.f, sp = 0.f, sy = 0.f;
    for (int i = blockIdx.x * 256 + tid; i < B * S / 4; i += 1024 * 256) {
        int b = i >> 16;               // S/4 = 65536 quads per image
        int s = (i & 65535) << 2;
        const float* nb = net + (size_t)b * 2 * S;
        float4 x0 = ld4s(nb + s);
        float4 x1 = ld4s(nb + S + s);
        int4 yv = *(const int4*)(yt + (size_t)b * S + s);
        float4 p, yf;
        p.x = 1.f / (1.f + expf(x0.x - x1.x));
        p.y = 1.f / (1.f + expf(x0.y - x1.y));
        p.z = 1.f / (1.f + expf(x0.z - x1.z));
        p.w = 1.f / (1.f + expf(x0.w - x1.w));
        yf.x = (float)yv.x; yf.y = (float)yv.y; yf.z = (float)yv.z; yf.w = (float)yv.w;
        st4s(J0 + (size_t)b * S + s, p);
        st4s(J0 + (size_t)(B + b) * S + s, yf);
        inter += p.x * yf.x + p.y * yf.y + p.z * yf.z + p.w * yf.w;
        sp += p.x + p.y + p.z + p.w;
        sy += yf.x + yf.y + yf.z + yf.w;
    }
    float v;
    v = blockReduce(inter, sw); if (tid == 0) pb[blockIdx.x * 3 + 0] = (double)v;
    v = blockReduce(sp, sw);    if (tid == 0) pb[blockIdx.x * 3 + 1] = (double)v;
    v = blockReduce(sy, sw);    if (tid == 0) pb[blockIdx.x * 3 + 2] = (double)v;
}

// ---------------------------------------------------------------- fused skeleton
// T=6 rounds per launch, 88x88 logical tile, SINGLE 90x88 LDS buffer (31.7 KB)
// updated in place -> 3 blocks/CU (24 waves) vs r4's 2 (16 waves).
// Per round: (a) read phase: dilate stash (old J core rows -> regs) + erode
// (6-row J window -> regs, E computed in regs); (b) barrier; write E in place;
// barrier; (c) dilate from buffer + delta vs stash + skel update in regs.
// In-place safety: round rr+1 reads rows 2(rr+1)..87-2(rr+1), a subset of the
// rows written in round rr ([rlo..rhi] = [1+2rr..86-2rr]); stale rows outside
// are never consumed (same creep argument as cols, proven r2-r4).
template <bool INIT>
__global__ __launch_bounds__(512, 6) void skel_fused_kernel(
        const float* __restrict__ Jin, float* __restrict__ Jout,
        float* __restrict__ skel, int r0) {
    __shared__ float Jl[LROWS * LDT];   // 90 x 88 floats = 31680 B
    const int tid = threadIdx.x;
    const int lane = tid & 63;
    const int img = blockIdx.x >> 6;
    const int t64 = blockIdx.x & 63;
    const int ty = t64 >> 3, tx = t64 & 7;
    const int y0 = ty * CORE - HALO, x0 = tx * CORE - HALO;
    const float* Ji = Jin + (size_t)img * S;
    float* Jo = Jout + (size_t)img * S;
    float* Sk = skel + (size_t)img * S;
    const bool interior = (ty > 0) & (ty < 7) & (tx > 0) & (tx < 7);

    // ---- load 88x88 J tile (quads all-in/out in x: x0 % 4 == 0)
    if (interior) {
        for (int i = tid; i < LDT * LDT / 4; i += 512) {
            int r = i / NQ, q = i - (i / NQ) * NQ;
            st4s(&Jl[r * LDT + (q << 2)],
                 ld4s(Ji + (y0 + r) * W + x0 + (q << 2)));
        }
    } else {
        for (int i = tid; i < LDT * LDT / 4; i += 512) {
            int r = i / NQ, q = i - (i / NQ) * NQ;
            int gy = y0 + r, gx = x0 + (q << 2);
            float4 v;
            if ((unsigned)gy < H && (unsigned)gx < W) v = ld4s(Ji + gy * W + gx);
            else v = make_float4(FINF, FINF, FINF, FINF);
            st4s(&Jl[r * LDT + (q << 2)], v);
        }
    }

    // ---- skel in registers: thread = 2-row core slab, rows {2ss,2ss+1}, quad sq
    const int sq = tid & 15, ss = tid >> 4;     // sq 0..15, ss 0..31
    const int tcol = HALO + (sq << 2);          // tile col of core quad
    const int gxc = tx * CORE + (sq << 2);      // global col of core quad
    const int row0 = ss << 1;                   // core row offset of slab
    float4 sk2[2];
    #pragma unroll
    for (int j = 0; j < 2; ++j) {
        if (INIT) sk2[j] = make_float4(0.f, 0.f, 0.f, 0.f);
        else      sk2[j] = ld4s(Sk + (ty * CORE + row0 + j) * W + gxc);
    }
    __syncthreads();

    for (int rr = r0; rr < 6; ++rr) {
        const int rlo = 1 + 2 * rr, rhi = 86 - 2 * rr;
        const int qlo = rlo >> 2, qhi = rhi >> 2;
        const int nq = qhi - qlo + 1;
        const int nslab = (rhi - rlo + 1 + 3) >> 2;
        const int nit = nslab * nq;             // <= 484 always

        // ---------------- READ PHASE ----------------
        // dilate stash: old J core rows (consumed for delta after overwrite)
        float4 Jst0 = ld4s(Jl + (row0 + 12) * LDT + tcol);
        float4 Jst1 = ld4s(Jl + (row0 + 13) * LDT + tcol);

        // erode: 4-row slab -> E in registers (rolling 3-row J window)
        float4 Ereg[4];
        int rb = 0, cc = 0, qq = 0;
        const bool active = (tid < nit);
        if (active) {
            int sb = tid / nq;
            qq = qlo + (tid - sb * nq);
            rb = rlo + (sb << 2);
            cc = qq << 2;
            const float* bp = Jl + (rb - 1) * LDT + cc;
            float4 wA = ld4s(bp);           // row rb-1
            float4 wB = ld4s(bp + LDT);     // row rb
            const bool cOOB = (!interior) && ((unsigned)(x0 + cc) >= W);
            #pragma unroll
            for (int j = 0; j < 4; ++j) {
                float4 wC = ld4s(bp + (j + 2) * LDT);   // row rb+j+1
                float lw = __shfl_up(wB.w, 1, 64);
                float rx = __shfl_down(wB.x, 1, 64);
                if (lane == 0 && qq != qlo)  lw = Jl[(rb + j) * LDT + cc - 1];
                if (lane == 63 && qq != qhi) rx = Jl[(rb + j) * LDT + cc + 4];
                if (qq == qlo) lw = FINF;   // tile-edge / creep col: safe
                if (qq == qhi) rx = FINF;   // creep col: safe
                float4 e;
                e.x = fminf(fminf(fminf(wA.x, wC.x), fminf(lw, wB.y)), wB.x);
                e.y = fminf(fminf(fminf(wA.y, wC.y), fminf(wB.x, wB.z)), wB.y);
                e.z = fminf(fminf(fminf(wA.z, wC.z), fminf(wB.y, wB.w)), wB.z);
                e.w = fminf(fminf(fminf(wA.w, wC.w), fminf(wB.z, rx)), wB.w);
                if (!interior) {
                    int gy = y0 + rb + j;
                    if (((unsigned)gy >= H) | cOOB)
                        e = make_float4(FINF, FINF, FINF, FINF);   // minpool pad
                }
                Ereg[j] = e;
                wA = wB; wB = wC;
            }
        }
        __syncthreads();   // all reads of old J complete

        // ---------------- WRITE PHASE (in place) ----------------
        if (active) {
            #pragma unroll
            for (int j = 0; j < 4; ++j)
                if (rb + j <= rhi) st4s(&Jl[(rb + j) * LDT + cc], Ereg[j]);
        }
        __syncthreads();   // E visible to all

        // ------- dilate (3x3 max) + delta + skel, 2-row slab per thread -------
        const bool last = (rr == 5);
        {
            const float* ebase = Jl + (row0 + 11) * LDT + tcol;
            float4 E[4];
            #pragma unroll
            for (int j = 0; j < 4; ++j) E[j] = ld4s(ebase + j * LDT);
            float lwv[4], rxv[4];
            #pragma unroll
            for (int j = 0; j < 4; ++j) {
                lwv[j] = __shfl_up(E[j].w, 1, 64);
                rxv[j] = __shfl_down(E[j].x, 1, 64);
                if (sq == 0)  lwv[j] = (tx == 0) ? -FINF : Jl[(row0 + 11 + j) * LDT + 11];
                if (sq == 15) rxv[j] = (tx == 7) ? -FINF : Jl[(row0 + 11 + j) * LDT + 76];
            }
            float4 hx[4];
            #pragma unroll
            for (int j = 0; j < 4; ++j) {
                hx[j].x = fmaxf(fmaxf(lwv[j], E[j].x), E[j].y);
                hx[j].y = fmaxf(fmaxf(E[j].x, E[j].y), E[j].z);
                hx[j].z = fmaxf(fmaxf(E[j].y, E[j].z), E[j].w);
                hx[j].w = fmaxf(fmaxf(E[j].z, E[j].w), rxv[j]);
            }
            #pragma unroll
            for (int j = 0; j < 2; ++j) {
                int gy = ty * CORE + row0 + j;
                float4 hm = hx[j], hp = hx[j + 2];
                if (!interior) {
                    if (gy == 0)     hm = make_float4(-FINF, -FINF, -FINF, -FINF);
                    if (gy == H - 1) hp = make_float4(-FINF, -FINF, -FINF, -FINF);
                }
                float4 dm;
                dm.x = fmaxf(fmaxf(hm.x, hx[j + 1].x), hp.x);
                dm.y = fmaxf(fmaxf(hm.y, hx[j + 1].y), hp.y);
                dm.z = fmaxf(fmaxf(hm.z, hx[j + 1].z), hp.z);
                dm.w = fmaxf(fmaxf(hm.w, hx[j + 1].w), hp.w);
                float4 Jv = (j == 0) ? Jst0 : Jst1;
                float d0 = fmaxf(Jv.x - dm.x, 0.f);
                float d1 = fmaxf(Jv.y - dm.y, 0.f);
                float d2 = fmaxf(Jv.z - dm.z, 0.f);
                float d3 = fmaxf(Jv.w - dm.w, 0.f);
                sk2[j].x += fmaxf(d0 - sk2[j].x * d0, 0.f);
                sk2[j].y += fmaxf(d1 - sk2[j].y * d1, 0.f);
                sk2[j].z += fmaxf(d2 - sk2[j].z * d2, 0.f);
                sk2[j].w += fmaxf(d3 - sk2[j].w * d3, 0.f);
                if (last) {
                    st4s(Jo + gy * W + gxc, E[j + 1]);   // Jout = erode at core
                    st4s(Sk + gy * W + gxc, sk2[j]);
                }
            }
        }
        if (!last) __syncthreads();   // dilate reads done before next overwrite
    }
}

// ---------------------------------------------------------------- endpoints
__global__ __launch_bounds__(256) void endpoint_kernel(
        const float* __restrict__ skel, double* __restrict__ acc) {
    __shared__ float sR[10][520];    // data at cols 4..515, zeros at 3 and 516
    __shared__ float sw[4];
    const int tid = threadIdx.x;
    const int img = blockIdx.x >> 6;
    const int rb = blockIdx.x & 63;
    const int yB = rb << 3;
    const float* Sk = skel + (size_t)img * S;
    for (int i = tid; i < 1280; i += 256) {
        int r = i >> 7, c4 = i & 127;
        int gy = yB - 1 + r;
        float4 v = make_float4(0.f, 0.f, 0.f, 0.f);
        if ((unsigned)gy < H) v = ld4s(Sk + gy * W + (c4 << 2));
        st4s(&sR[r][4 + (c4 << 2)], v);
    }
    if (tid < 10) { sR[tid][3] = 0.f; sR[tid][516] = 0.f; }
    __syncthreads();
    float t = 0.f, syA = 0.f, sxA = 0.f;
    #pragma unroll
    for (int k = 0; k < 4; ++k) {
        int qidx = k * 256 + tid;
        int rrow = qidx >> 7;            // 0..7
        int x = (qidx & 127) << 2;
        int r = 1 + rrow;
        float gy = (float)(yB + rrow);
        const float* Rm = &sR[r - 1][4 + x];
        const float* Rc = &sR[r][4 + x];
        const float* Rp = &sR[r + 1][4 + x];
        float4 bm = ld4s(Rm); float lm = ld4s(Rm - 4).w, rm = ld4s(Rm + 4).x;
        float4 bc = ld4s(Rc); float lc = ld4s(Rc - 4).w, rc = ld4s(Rc + 4).x;
        float4 bp = ld4s(Rp); float lp = ld4s(Rp - 4).w, rp = ld4s(Rp + 4).x;
        float hm0 = lm + bm.x + bm.y, hm1 = bm.x + bm.y + bm.z;
        float hm2 = bm.y + bm.z + bm.w, hm3 = bm.z + bm.w + rm;
        float hc0 = lc + bc.x + bc.y, hc1 = bc.x + bc.y + bc.z;
        float hc2 = bc.y + bc.z + bc.w, hc3 = bc.z + bc.w + rc;
        float hp0 = lp + bp.x + bp.y, hp1 = bp.x + bp.y + bp.z;
        float hp2 = bp.y + bp.z + bp.w, hp3 = bp.z + bp.w + rp;
        float ns0 = hm0 + hc0 + hp0 + 9.f * bc.x;
        float ns1 = hm1 + hc1 + hp1 + 9.f * bc.y;
        float ns2 = hm2 + hc2 + hp2 + 9.f * bc.z;
        float ns3 = hm3 + hc3 + hp3 + 9.f * bc.w;
        float e0 = ns0 - 11.f, e1 = ns1 - 11.f, e2 = ns2 - 11.f, e3 = ns3 - 11.f;
        float ep0 = expf(-e0 * e0) * bc.x;
        float ep1 = expf(-e1 * e1) * bc.y;
        float ep2 = expf(-e2 * e2) * bc.z;
        float ep3 = expf(-e3 * e3) * bc.w;
        float es = ep0 + ep1 + ep2 + ep3;
        t += es;
        syA += gy * es;
        sxA += ep0 * (float)(x + 0) + ep1 * (float)(x + 1)
             + ep2 * (float)(x + 2) + ep3 * (float)(x + 3);
    }
    float v;
    v = blockReduce(t, sw);   if (tid == 0) atomicAdd(&acc[img * 3 + 0], (double)v);
    v = blockReduce(syA, sw); if (tid == 0) atomicAdd(&acc[img * 3 + 1], (double)v);
    v = blockReduce(sxA, sw); if (tid == 0) atomicAdd(&acc[img * 3 + 2], (double)v);
}

// ---------------------------------------------------------------- final scalar
__global__ __launch_bounds__(256) void final_kernel(
        const double* __restrict__ acc, const double* __restrict__ pb,
        float* __restrict__ out) {
    const int tid = threadIdx.x;
    double si = 0.0, sp = 0.0, sy = 0.0;
    for (int i = tid; i < 1024; i += 256) {
        si += pb[i * 3 + 0]; sp += pb[i * 3 + 1]; sy += pb[i * 3 + 2];
    }
    #pragma unroll
    for (int o = 32; o; o >>= 1) {
        si += __shfl_down(si, o, 64);
        sp += __shfl_down(sp, o, 64);
        sy += __shfl_down(sy, o, 64);
    }
    __shared__ double dsw[3][4];
    int lane = tid & 63, wid = tid >> 6;
    if (lane == 0) { dsw[0][wid] = si; dsw[1][wid] = sp; dsw[2][wid] = sy; }
    __syncthreads();
    if (tid == 0) {
        double inter = dsw[0][0] + dsw[0][1] + dsw[0][2] + dsw[0][3];
        double sump  = dsw[1][0] + dsw[1][1] + dsw[1][2] + dsw[1][3];
        double sumy  = dsw[2][0] + dsw[2][1] + dsw[2][2] + dsw[2][3];
        double dsum = 0.0, csum = 0.0;
        for (int b = 0; b < B; ++b) {
            double tp = acc[b * 3 + 0], typ = acc[b * 3 + 1], txp = acc[b * 3 + 2];
            double tt = acc[(B + b) * 3 + 0], tyt = acc[(B + b) * 3 + 1], txt = acc[(B + b) * 3 + 2];
            double ycp = typ / (tp + 1e-8), xcp = txp / (tp + 1e-8);
            double yct = tyt / (tt + 1e-8), xct = txt / (tt + 1e-8);
            double dy = ycp - yct, dx = xcp - xct;
            dsum += sqrt(dy * dy + dx * dx);
            csum += fabs(tp - tt) / (tp + tt + 1e-8);
        }
        double diag = sqrt((double)(H * H + W * W));
        double distance_loss = (dsum / B) / (diag + 1e-8);
        double count_penalty = csum / B;
        double dice = 1.0 - (2.0 * inter + 1.0) / (sumy + sump + 1.0);
        out[0] = (float)(0.85 * dice + 0.15 * (distance_loss + count_penalty));
    }
}

// ---------------------------------------------------------------- launch
extern "C" void kernel_launch(void* const* d_in, const int* in_sizes, int n_in,
                              void* d_out, int out_size, void* d_ws, size_t ws_size,
                              hipStream_t stream) {
    const float* net = (const float*)d_in[0];   // [8,2,512,512] f32
    const int*   yt  = (const int*)d_in[1];     // [8,1,512,512] i32
    float* out = (float*)d_out;

    float* J0   = (float*)d_ws;                       // 16 MB
    float* J1   = J0 + (size_t)NIMG * S;              // 16 MB
    float* skel = J1 + (size_t)NIMG * S;              // 16 MB
    double* acc = (double*)(skel + (size_t)NIMG * S); // 48 doubles
    double* pb  = acc + 48;                           // 1024*3 doubles

    phase1_kernel<<<1024, 256, 0, stream>>>(net, yt, J0, pb, acc);

    // 41 rounds = 6+6+6+6+6+6+5
    skel_fused_kernel<true><<<NIMG * 64, 512, 0, stream>>>(J0, J1, skel, 0);
    float* a = J1; float* b = J0;
    for (int p = 1; p < 7; ++p) {
        int r0 = (p == 6) ? 1 : 0;   // last phase: 5 rounds (rr = 1..5)
        skel_fused_kernel<false><<<NIMG * 64, 512, 0, stream>>>(a, b, skel, r0);
        float* tmp = a; a = b; b = tmp;
    }

    endpoint_kernel<<<NIMG * 64, 256, 0, stream>>>(skel, acc);
    final_kernel<<<1, 256, 0, stream>>>(acc, pb, out);
}